// Round 13
// baseline (3971.959 us; speedup 1.0000x reference)
//
#include <hip/hip_runtime.h>
#include <stdint.h>

#define NB 16
#define HH 128
#define WW 128
#define L (HH*WW)        // 16384
#define CIN 3
#define HID 256
#define NC 21
#define CHUNK 256
#define WARM 512
#define NCHUNKS (L/CHUNK)   // 64
#define T_PER 32            // t's per wave in k_bp
#define NPACK (L/4)         // 4096 packs of 4 timesteps

// ---------------- K1: conv -> fp32 emissions, stored TRANSPOSED em_T[b][c][t] ----------------
// fp64 accumulate (round once to fp32 = correctly rounded), fp32 elementwise bias in ref order.
__global__ __launch_bounds__(256) void k_conv(
    const float* __restrict__ x, const float* __restrict__ w1,
    const float* __restrict__ b1, const float* __restrict__ w2,
    const float* __restrict__ b2, float* __restrict__ emT)
{
    int tid = threadIdx.x;
    int g  = blockIdx.x * 256 + tid;      // 0..B*L-1
    int b  = g >> 14;
    int t  = g & (L-1);
    int y  = t >> 7;
    int xx = t & (WW-1);

    double p[27];
    const float* xb = x + (size_t)b * CIN * L;
    #pragma unroll
    for (int ic = 0; ic < CIN; ++ic) {
        #pragma unroll
        for (int ky = 0; ky < 3; ++ky) {
            #pragma unroll
            for (int kx = 0; kx < 3; ++kx) {
                int yy = y + ky - 1, xc = xx + kx - 1;
                float v = 0.f;
                if (yy >= 0 && yy < HH && xc >= 0 && xc < WW)
                    v = xb[ic * L + yy * WW + xc];
                p[ic*9 + ky*3 + kx] = (double)v;
            }
        }
    }

    double acc[NC];
    #pragma unroll
    for (int c = 0; c < NC; ++c) acc[c] = 0.0;

    // unroll 2: pipelines the wave-uniform (scalar) weight loads behind fp64 FMAs.
    // Per-accumulator FP op order unchanged -> bit-identical results.
    #pragma unroll 2
    for (int oc = 0; oc < HID; ++oc) {
        double hv = 0.0;                              // conv1 accum
        #pragma unroll
        for (int j = 0; j < 27; ++j) hv += (double)w1[oc*27 + j] * p[j];
        float h32 = (float)hv;                        // round conv1 to fp32
        h32 = h32 + b1[oc];                           // fp32 elementwise bias
        h32 = fmaxf(h32, 0.f);                        // relu (fp32)
        double hd = (double)h32;
        #pragma unroll
        for (int c = 0; c < NC; ++c) acc[c] += (double)w2[c*HID + oc] * hd;
    }
    float* dstb = emT + (size_t)b * NC * L;
    #pragma unroll
    for (int c = 0; c < NC; ++c) {
        float e32 = (float)acc[c];                    // round conv2 to fp32
        dstb[(size_t)c * L + t] = e32 + b2[c];        // transposed store (coalesced in t)
    }
}

// ---------------- K2a: p-split bpermute recursion, TWO batch chains interleaved per wave ----------------
// s'[n] = fl( max_p fl(s[p]+T[p][n]) + e[n] ) — bitwise equal to ref by RNE monotonicity.
// R11 (one chain) = 314 cyc/step: ~84 issue + 2 dependent DS-latency levels (~120 each).
// Latency-bound => interleave a second independent batch chain IN THE SAME LANES: its
// ~84 cyc of issue fills the first chain's DS waits (R8's readlane version couldn't gain
// because readlanes are issue-bound; bpermute gathers are pipelined). tc/ga/ca shared.
__global__ __launch_bounds__(64) void k_scores(
    const float* __restrict__ emT, const float* __restrict__ start,
    const float* __restrict__ endt, const float* __restrict__ trans,
    float* __restrict__ sc, int* __restrict__ last_tag)
{
    __shared__ float fin[64];
    int l  = threadIdx.x;
    int bA = blockIdx.x * 2;
    int bB = bA + 1;
    int g = l / 21; if (g > 2) g = 2;        // lane 63 shadows (g=2,n=20)
    int n = l - g*21; if (n > 20) n = 20;

    const float4* erA = (const float4*)(emT + ((size_t)bA * NC + n) * L);
    const float4* erB = (const float4*)(emT + ((size_t)bB * NC + n) * L);
    float* scpA = sc + (size_t)bA * NC * L;          // 84 floats per pack
    float* scpB = sc + (size_t)bB * NC * L;

    float tc[7];
    #pragma unroll
    for (int i = 0; i < 7; ++i) tc[i] = trans[(g*7 + i)*NC + n];
    #pragma unroll
    for (int i = 0; i < 7; ++i) asm volatile("" : "+v"(tc[i]));   // pin in VGPRs

    int ga[7];
    #pragma unroll
    for (int i = 0; i < 7; ++i) ga[i] = (g*7 + i) * 4;    // gather addrs (copy-0 lanes)
    #pragma unroll
    for (int i = 0; i < 7; ++i) asm volatile("" : "+v"(ga[i]));
    int g1 = g + 1; if (g1 > 2) g1 -= 3;
    int g2 = g + 2; if (g2 > 2) g2 -= 3;
    int ca1 = (n + 21*g1) * 4;                            // combine addrs (other copies)
    int ca2 = (n + 21*g2) * 4;
    asm volatile("" : "+v"(ca1), "+v"(ca2));

    float svA, svB;   // my state's current score, per chain

    #define BPERM(A,V) __int_as_float(__builtin_amdgcn_ds_bpermute((A), __float_as_int(V)))

    // Both chains' gathers issued back-to-back; fine-grained lgkmcnt lets A's tree
    // overlap B's in-flight gathers, and B's tree overlap A's combine level.
    #define STEP2(EVA, EVB, OUTA, OUTB) { \
        float x0 = BPERM(ga[0], svA), y0 = BPERM(ga[0], svB); \
        float x1 = BPERM(ga[1], svA), y1 = BPERM(ga[1], svB); \
        float x2 = BPERM(ga[2], svA), y2 = BPERM(ga[2], svB); \
        float x3 = BPERM(ga[3], svA), y3 = BPERM(ga[3], svB); \
        float x4 = BPERM(ga[4], svA), y4 = BPERM(ga[4], svB); \
        float x5 = BPERM(ga[5], svA), y5 = BPERM(ga[5], svB); \
        float x6 = BPERM(ga[6], svA), y6 = BPERM(ga[6], svB); \
        x0 += tc[0]; x1 += tc[1]; x2 += tc[2]; x3 += tc[3]; \
        x4 += tc[4]; x5 += tc[5]; x6 += tc[6]; \
        float pa = fmaxf(fmaxf(x0, x1), x2); \
        float pb = fmaxf(fmaxf(x3, x4), x5); \
        float prA = fmaxf(fmaxf(pa, pb), x6);       /* exact max over my 7 p's (A) */ \
        float oA1 = BPERM(ca1, prA); \
        float oA2 = BPERM(ca2, prA); \
        y0 += tc[0]; y1 += tc[1]; y2 += tc[2]; y3 += tc[3]; \
        y4 += tc[4]; y5 += tc[5]; y6 += tc[6]; \
        float qa = fmaxf(fmaxf(y0, y1), y2); \
        float qb = fmaxf(fmaxf(y3, y4), y5); \
        float prB = fmaxf(fmaxf(qa, qb), y6);       /* exact max over my 7 p's (B) */ \
        float oB1 = BPERM(ca1, prB); \
        float oB2 = BPERM(ca2, prB); \
        OUTA = fmaxf(fmaxf(prA, oA1), oA2) + (EVA); /* exact 21-max, then fl(+e) */ \
        svA = OUTA; \
        OUTB = fmaxf(fmaxf(prB, oB1), oB2) + (EVB); \
        svB = OUTB; }

    float4 eA0 = erA[0], eA1 = erA[1];
    float4 eB0 = erB[0], eB1 = erB[1];

    // ---- pack 0 (t=0 init + t=1..3) ----
    float v0A = eA0.x + start[n];      // s0 = fl(em[0]+start), ref order
    float v0B = eB0.x + start[n];
    svA = v0A;  svB = v0B;
    {
        float4 evA = eA0, evB = eB0;
        eA0 = erA[2];  eB0 = erB[2];
        float a1v, a2v, a3v, b1v, b2v, b3v;
        STEP2(evA.y, evB.y, a1v, b1v)
        STEP2(evA.z, evB.z, a2v, b2v)
        STEP2(evA.w, evB.w, a3v, b3v)
        if (l < NC) {
            *(float4*)(scpA + n*4) = make_float4(v0A, a1v, a2v, a3v);
            *(float4*)(scpB + n*4) = make_float4(v0B, b1v, b2v, b3v);
        }
    }

    // ---- packs 1..4095 ----
    for (int k = 1; k < NPACK; ++k) {
        float4 evA = (k & 1) ? eA1 : eA0;
        float4 evB = (k & 1) ? eB1 : eB0;
        int kp = k + 2; if (kp > NPACK-1) kp = NPACK-1;
        if (k & 1) { eA1 = erA[kp]; eB1 = erB[kp]; }
        else       { eA0 = erA[kp]; eB0 = erB[kp]; }

        float a0v, a1v, a2v, a3v, b0v, b1v, b2v, b3v;
        STEP2(evA.x, evB.x, a0v, b0v)
        STEP2(evA.y, evB.y, a1v, b1v)
        STEP2(evA.z, evB.z, a2v, b2v)
        STEP2(evA.w, evB.w, a3v, b3v)
        if (l < NC) {
            *(float4*)(scpA + k*84 + n*4) = make_float4(a0v, a1v, a2v, a3v);
            *(float4*)(scpB + k*84 + n*4) = make_float4(b0v, b1v, b2v, b3v);
        }
    }
    #undef STEP2
    #undef BPERM

    if (l < NC) { fin[n] = svA; fin[32 + n] = svB; }
    __syncthreads();
    if (l == 0) {
        float bvA = fin[0]  + endt[0]; int btA = 0;
        float bvB = fin[32] + endt[0]; int btB = 0;
        #pragma unroll
        for (int j = 1; j < NC; ++j) {
            float vA = fin[j] + endt[j];
            if (vA > bvA) { bvA = vA; btA = j; }
            float vB = fin[32 + j] + endt[j];
            if (vB > bvB) { bvB = vB; btB = j; }
        }
        last_tag[bA] = btA;
        last_tag[bB] = btB;
    }
}

// ---------------- K2b: parallel backpointer recovery ----------------
// bp[t][n] = first p with fl(fl(s_{t-1}[p]+T[p][n])+e[t][n]) == s_t[n]
__global__ __launch_bounds__(256) void k_bp(
    const float* __restrict__ emT, const float* __restrict__ sc,
    const float* __restrict__ trans, uint8_t* __restrict__ bp)
{
    int wave = threadIdx.x >> 6;
    int lane = threadIdx.x & 63;
    int ne   = lane < NC ? lane : NC-1;

    int bidx  = blockIdx.x;
    int b     = bidx >> 7;                              // 128 blocks per batch
    int tbase = (bidx & 127) * (4*T_PER) + wave*T_PER;

    const float* emb = emT + (size_t)b * NC * L;
    const float* scp = sc  + (size_t)b * NC * L;
    uint8_t*     bpb = bp  + (size_t)b * L * NC;

    float tc[NC];
    #pragma unroll
    for (int pp = 0; pp < NC; ++pp) tc[pp] = trans[pp*NC + ne];

    for (int t = tbase; t < tbase + T_PER; ++t) {
        if (t == 0) continue;
        float target = scp[(t>>2)*84 + ne*4 + (t&3)];
        float e      = emb[(size_t)ne * L + t];
        const float* sp = scp + ((t-1)>>2)*84 + ((t-1)&3);
        int fi = 0;
        #pragma unroll
        for (int pp = NC-1; pp >= 0; --pp) {
            float cand = (sp[pp*4] + tc[pp]) + e;
            if (cand == target) fi = pp;
        }
        if (lane < NC) bpb[(size_t)t * NC + ne] = (uint8_t)fi;
    }
}

// ---------------- K3: chunk-parallel backtrack (integer, exact) ----------------
__global__ __launch_bounds__(64) void k_backtrack(
    const uint8_t* __restrict__ bp, const int* __restrict__ last_tag,
    int* __restrict__ out)
{
    int blk = blockIdx.x;
    int b   = blk >> 6;
    int k   = blk & (NCHUNKS-1);
    int cs  = k * CHUNK;
    int ce  = cs + CHUNK;
    int sp  = ce - 1 + WARM; if (sp > L-1) sp = L-1;
    int tag = (sp == L-1) ? last_tag[b] : 0;
    const uint8_t* bpb = bp + (size_t)b * L * NC;
    int* ob = out + (size_t)b * L;
    for (int t = sp;; --t) {
        if (t < ce) { if (threadIdx.x == 0) ob[t] = tag; }
        if (t == cs) break;
        tag = (int)bpb[(size_t)t * NC + tag];
    }
}

extern "C" void kernel_launch(void* const* d_in, const int* in_sizes, int n_in,
                              void* d_out, int out_size, void* d_ws, size_t ws_size,
                              hipStream_t stream) {
    const float* x  = (const float*)d_in[0];
    const float* w1 = (const float*)d_in[1];
    const float* b1 = (const float*)d_in[2];
    const float* w2 = (const float*)d_in[3];
    const float* b2 = (const float*)d_in[4];
    const float* st = (const float*)d_in[5];
    const float* en = (const float*)d_in[6];
    const float* tr = (const float*)d_in[7];
    int* out = (int*)d_out;

    char* ws = (char*)d_ws;
    float*   em = (float*)ws;                                    // em_T: 22,020,096 B
    float*   sc = (float*)(ws + (size_t)NB*L*NC*4);              // packed scores: 22,020,096 B
    uint8_t* bp = (uint8_t*)(ws + (size_t)NB*L*NC*8);            // 5,505,024 B
    int*     lt = (int*)(ws + (size_t)NB*L*NC*9);                // int[NB]

    k_conv     <<<dim3(NB*L/256),   dim3(256), 0, stream>>>(x, w1, b1, w2, b2, em);
    k_scores   <<<dim3(NB/2),       dim3(64),  0, stream>>>(em, st, en, tr, sc, lt);
    k_bp       <<<dim3(NB*128),     dim3(256), 0, stream>>>(em, sc, tr, bp);
    k_backtrack<<<dim3(NB*NCHUNKS), dim3(64),  0, stream>>>(bp, lt, out);
}